// Round 5
// baseline (122.599 us; speedup 1.0000x reference)
//
#include <hip/hip_runtime.h>

#define B_    32
#define H_    640
#define W_    368
#define OH    634          // H - 6
#define OW    362          // W - 6
#define CHUNK 10           // output rows per block; 2048 blocks = 8/CU, 24 waves/CU
#define NCHUNK 64          // 63 full chunks + last (4 rows); 63*10+4 = 634
#define NBLK  (NCHUNK * B_)          // 2048
#define GROUPS 64

// d_ws layout (floats):
//   [0..31]      per-batch max of target (int-bits atomicMax; 0xAA poison is negative,
//                any positive-float bits win, so no pre-zeroing needed)
//   [64..1087]   64 partial-sum slots, stride 16 floats (64 B); zeroed by k_max blk 0
//
// R1/R2 lesson: no device-scope __threadfence per block (~70 ns serialized each).
// R4 lesson: no per-row __syncthreads either — its implicit vmcnt(0) drains the
// async stage queue every row (+3 us vs R3). This version: wave-private LDS rings
// + counted vmcnt(6) (never 0 in loop), zero barriers in the main loop.
#define SLOT0 64
#define STRIDE 16

typedef float f2 __attribute__((ext_vector_type(2)));

__global__ __launch_bounds__(256) void k_max(const float* __restrict__ tgt,
                                             float* __restrict__ ws) {
    if (blockIdx.x == 0) {                     // zero slots (stream order vs k_ssim)
        for (int i = threadIdx.x; i < GROUPS * STRIDE; i += 256)
            ws[SLOT0 + i] = 0.0f;
    }
    const int b   = blockIdx.x >> 5;
    const int seg = blockIdx.x & 31;
    const int perseg = (H_ * W_) / 32;         // 7360 floats
    const float4* p = (const float4*)(tgt + (size_t)b * (H_ * W_) + (size_t)seg * perseg);
    const int n4 = perseg / 4;                 // 1840
    float m = 0.0f;
    for (int i = threadIdx.x; i < n4; i += 256) {
        float4 v = p[i];
        m = fmaxf(m, fmaxf(fmaxf(v.x, v.y), fmaxf(v.z, v.w)));
    }
    #pragma unroll
    for (int off = 32; off; off >>= 1)
        m = fmaxf(m, __shfl_down(m, off, 64));
    __shared__ float sm[4];
    const int lane = threadIdx.x & 63, wv = threadIdx.x >> 6;
    if (lane == 0) sm[wv] = m;
    __syncthreads();
    if (threadIdx.x == 0) {
        m = fmaxf(fmaxf(sm[0], sm[1]), fmaxf(sm[2], sm[3]));
        atomicMax((int*)ws + b, __float_as_int(m));   // inputs >= 0
    }
}

// Stage one row's 136-float (X,Y) window for THIS WAVE into its private LDS slot.
// 2 VMEM instrs/row/wave; vmcnt is per-wave, so counted waits need no barriers.
// Lane l loads 16 B from rowbase + 16*l; LDS dest = base + 16*l (m104 linear rule).
__device__ __forceinline__ void stage_row(const float* __restrict__ xrow,
                                          const float* __restrict__ yrow,
                                          float* ldsX, float* ldsY,
                                          int lane, int nl) {
    if (lane < nl) {   // exec-masked; nl>0 always so both instrs issue (vmcnt +2)
        __builtin_amdgcn_global_load_lds(
            (const __attribute__((address_space(1))) void*)(xrow + lane * 4),
            (__attribute__((address_space(3))) void*)ldsX, 16, 0, 0);
        __builtin_amdgcn_global_load_lds(
            (const __attribute__((address_space(1))) void*)(yrow + lane * 4),
            (__attribute__((address_space(3))) void*)ldsY, 16, 0, 0);
    }
}

// Horizontal 7-sums for TWO adjacent windows (cols cc..cc+6, cc+1..cc+7).
// h = {x0,x1, y0,y1, s0,s1 (xx+yy), xy0,xy1}; xx,yy share one accumulator.
__device__ __forceinline__ void hsum2v(const f2 xn[4], const f2 yn[4], float h[8]) {
    const float xs[8] = {xn[0].x, xn[0].y, xn[1].x, xn[1].y, xn[2].x, xn[2].y, xn[3].x, xn[3].y};
    const float ys[8] = {yn[0].x, yn[0].y, yn[1].x, yn[1].y, yn[2].x, yn[2].y, yn[3].x, yn[3].y};
    float hx = 0, hy = 0, hs = 0, hxy = 0;
    #pragma unroll
    for (int k = 0; k < 7; ++k) {
        const float xv = xs[k], yv = ys[k];
        hx += xv; hy += yv;
        hs  = fmaf(xv, xv, hs);
        hs  = fmaf(yv, yv, hs);
        hxy = fmaf(xv, yv, hxy);
    }
    h[0] = hx;  h[1] = hx - xs[0] + xs[7];
    h[2] = hy;  h[3] = hy - ys[0] + ys[7];
    h[4] = hs;
    h[5] = fmaf(xs[7], xs[7], fmaf(ys[7], ys[7], fmaf(-xs[0], xs[0], fmaf(-ys[0], ys[0], hs))));
    h[6] = hxy; h[7] = fmaf(xs[7], ys[7], fmaf(-xs[0], ys[0], hxy));
}

__device__ __forceinline__ void loadlds(const float* bx, const float* by,
                                        int cc, f2 xn[4], f2 yn[4]) {
    const f2* xp = (const f2*)(bx + cc);   // stride-8B lanes -> 2-way bank alias (free, m136)
    const f2* yp = (const f2*)(by + cc);
    xn[0] = xp[0]; xn[1] = xp[1]; xn[2] = xp[2]; xn[3] = xp[3];
    yn[0] = yp[0]; yn[1] = yp[1]; yn[2] = yp[2]; yn[3] = yp[3];
}

// Per-wave software pipeline, depth 3: stage row k+3 -> vmcnt(6) (oldest stage
// retired, m135 in-order retire) -> consume row k from wave-private LDS slot.
// sched_barrier(0) fences (rule #18): pins prior consume before the slot rewrite,
// and pins ds_reads after the vmcnt wait.
__global__ __launch_bounds__(192) void k_ssim(const float* __restrict__ X,
                                              const float* __restrict__ Y,
                                              float* __restrict__ ws) {
    const int t    = threadIdx.x;              // 0..191
    const int w    = t >> 6;                   // wave 0,1,2 -> col groups
    const int lane = t & 63;
    const int b    = blockIdx.y;
    const int r0   = blockIdx.x * CHUNK;
    const int outRows = min(CHUNK, OH - r0);   // 10, or 4 for last chunk
    const int c0   = w << 7;                   // 0,128,256
    const int cc   = lane << 1;                // col within wave window
    const bool colOK = (c0 + cc) < OW;         // wave2: lane<53
    const int nl   = (w < 2) ? 34 : 28;        // stage lanes: 136 / 112 floats

    __shared__ float buf[3][4][2][144];        // [wave][slot][X|Y][floats] = 13.8 KB

    const float dr  = ws[b];
    float C1 = 0.01f * dr; C1 *= C1;
    float C2 = 0.03f * dr; C2 *= C2;
    const float c1s = C1 * 2401.0f;            // scaled-domain constants (u* scale cancels)
    const float c2s = C2 * 2401.0f;
    const float covn2 = 2.0f * (49.0f / 48.0f);
    const float covn  = 49.0f / 48.0f;

    const float* Xw = X + (size_t)b * (H_ * W_) + c0;
    const float* Yw = Y + (size_t)b * (H_ * W_) + c0;

    // prologue: stage rows 0,1,2 into slots 0,1,2 (6 VMEM outstanding)
    #pragma unroll
    for (int s = 0; s < 3; ++s)
        stage_row(Xw + (size_t)(r0 + s) * W_, Yw + (size_t)(r0 + s) * W_,
                  &buf[w][s][0][0], &buf[w][s][1][0], lane, nl);

    float acc = 0.0f;
    float ring[4][7][2];                       // [quantity][row slot][col] — compile-time idx
    float tot[4][2] = {};
    float h[8];
    f2 xn[4], yn[4];

    #pragma unroll
    for (int p = 0; p < 6; ++p) {              // prime 6 halo rows (consume k=p)
        __builtin_amdgcn_sched_barrier(0);     // prior consume (lgkm-waited) stays above
        stage_row(Xw + (size_t)(r0 + p + 3) * W_, Yw + (size_t)(r0 + p + 3) * W_,
                  &buf[w][(p + 3) & 3][0][0], &buf[w][(p + 3) & 3][1][0], lane, nl);
        asm volatile("s_waitcnt vmcnt(6)" ::: "memory");   // row p's 2 loads retired
        __builtin_amdgcn_sched_barrier(0);
        if (colOK) {
            loadlds(&buf[w][p & 3][0][0], &buf[w][p & 3][1][0], cc, xn, yn);
            hsum2v(xn, yn, h);
            #pragma unroll
            for (int q = 0; q < 4; ++q) {
                ring[q][p][0] = h[2 * q];     ring[q][p][1] = h[2 * q + 1];
                tot[q][0] += h[2 * q];        tot[q][1] += h[2 * q + 1];
            }
        }
    }

    for (int ii = 0; ii < outRows; ii += 7) {
        #pragma unroll
        for (int p = 0; p < 7; ++p) {          // ring slot == p (compile-time)
            const int i = ii + p;
            if (i >= outRows) break;           // block-uniform
            __builtin_amdgcn_sched_barrier(0); // prior consume stays above slot rewrite
            if (i + 3 < outRows) {             // stage row i+9 (consume k=i+6, depth 3)
                const int r = i + 9;
                stage_row(Xw + (size_t)(r0 + r) * W_, Yw + (size_t)(r0 + r) * W_,
                          &buf[w][r & 3][0][0], &buf[w][r & 3][1][0], lane, nl);
                asm volatile("s_waitcnt vmcnt(6)" ::: "memory");
            } else {
                asm volatile("s_waitcnt vmcnt(0)" ::: "memory");   // tail drain (3 rows)
            }
            __builtin_amdgcn_sched_barrier(0);
            if (colOK) {
                loadlds(&buf[w][(i + 6) & 3][0][0], &buf[w][(i + 6) & 3][1][0], cc, xn, yn);
                hsum2v(xn, yn, h);

                #pragma unroll
                for (int q = 0; q < 4; ++q) {
                    tot[q][0] += h[2 * q];    tot[q][1] += h[2 * q + 1];
                }

                #pragma unroll
                for (int j = 0; j < 2; ++j) {
                    const float tx = tot[0][j], ty = tot[1][j];
                    const float ts = tot[2][j], txy = tot[3][j];
                    const float pxy = tx * ty;
                    const float A1  = fmaf(pxy, 2.0f, c1s);
                    const float s2  = fmaf(tx, tx, ty * ty);
                    const float B1  = s2 + c1s;
                    const float mxy = fmaf(49.0f, txy, -pxy);
                    const float A2  = fmaf(covn2, mxy, c2s);
                    const float vs  = fmaf(49.0f, ts, -s2);
                    const float B2  = fmaf(covn, vs, c2s);
                    acc = fmaf(A1 * A2, __builtin_amdgcn_rcpf(B1 * B2), acc);
                }

                const int sn = (p + 6) % 7;    // retire slot p, insert new in slot sn
                #pragma unroll
                for (int q = 0; q < 4; ++q) {
                    tot[q][0] -= ring[q][p][0];  tot[q][1] -= ring[q][p][1];
                    ring[q][sn][0] = h[2 * q];   ring[q][sn][1] = h[2 * q + 1];
                }
            }
        }
    }

    // wave reduce, LDS across 3 waves, ONE scattered atomic per block. No fences!
    #pragma unroll
    for (int off = 32; off; off >>= 1)
        acc += __shfl_down(acc, off, 64);
    __shared__ float sm[3];
    if (lane == 0) sm[w] = acc;
    __syncthreads();
    if (t == 0) {
        const float s = sm[0] + sm[1] + sm[2];
        const int blk = blockIdx.y * NCHUNK + blockIdx.x;
        atomicAdd(ws + SLOT0 + (blk & (GROUPS - 1)) * STRIDE, s);  // 64 independent lines
    }
}

__global__ __launch_bounds__(64) void k_fin(const float* __restrict__ ws,
                                            float* __restrict__ out) {
    float v = ws[SLOT0 + threadIdx.x * STRIDE];   // kernel boundary orders prior atomics
    #pragma unroll
    for (int off = 32; off; off >>= 1)
        v += __shfl_down(v, off, 64);
    if (threadIdx.x == 0)
        out[0] = 1.0f - v * (1.0f / (32.0f * 634.0f * 362.0f));
}

extern "C" void kernel_launch(void* const* d_in, const int* in_sizes, int n_in,
                              void* d_out, int out_size, void* d_ws, size_t ws_size,
                              hipStream_t stream) {
    const float* X = (const float*)d_in[0];   // 'output'
    const float* Y = (const float*)d_in[1];   // 'target'
    float* ws = (float*)d_ws;

    k_max<<<dim3(1024), dim3(256), 0, stream>>>(Y, ws);
    k_ssim<<<dim3(NCHUNK, B_), dim3(192), 0, stream>>>(X, Y, ws);
    k_fin<<<dim3(1), dim3(64), 0, stream>>>(ws, (float*)d_out);
}

// Round 6
// 111.924 us; speedup vs baseline: 1.0954x; 1.0954x over previous
//
#include <hip/hip_runtime.h>

#define B_    32
#define H_    640
#define W_    368
#define OH    634          // H - 6
#define OW    362          // W - 6
#define CHUNK 10           // output rows per block; 2048 blocks = 8/CU, 6 waves/SIMD
#define NCHUNK 64          // 63 full chunks + last (4 rows); 63*10+4 = 634
#define NBLK  (NCHUNK * B_)          // 2048
#define GROUPS 64

// d_ws layout (floats):
//   [0..31]      per-batch max of target (int-bits atomicMax; 0xAA poison is negative,
//                any positive-float bits win, so no pre-zeroing needed)
//   [64..1087]   64 partial-sum slots, stride 16 floats (64 B); zeroed by k_max blk 0
//
// Session lessons baked in:
//  R1/R2: no per-block device-scope __threadfence (~70 ns serialized each; +110 us).
//  R4:    no per-row __syncthreads (implicit vmcnt(0) drains the stage queue; +3 us).
//  R5:    LDS staging + counted vmcnt is NEUTRAL vs R3's register prefetch -> kernel
//         is VALU-issue-bound, not latency-bound. This round: packed-FP32 math
//         (v_pk_fma_f32 etc.) to cut VALU instruction count ~33%.
#define SLOT0 64
#define STRIDE 16

typedef float f2 __attribute__((ext_vector_type(2)));

__global__ __launch_bounds__(256) void k_max(const float* __restrict__ tgt,
                                             float* __restrict__ ws) {
    if (blockIdx.x == 0) {                     // zero slots (stream order vs k_ssim)
        for (int i = threadIdx.x; i < GROUPS * STRIDE; i += 256)
            ws[SLOT0 + i] = 0.0f;
    }
    const int b   = blockIdx.x >> 5;
    const int seg = blockIdx.x & 31;
    const int perseg = (H_ * W_) / 32;         // 7360 floats
    const float4* p = (const float4*)(tgt + (size_t)b * (H_ * W_) + (size_t)seg * perseg);
    const int n4 = perseg / 4;                 // 1840
    float m = 0.0f;
    for (int i = threadIdx.x; i < n4; i += 256) {
        float4 v = p[i];
        m = fmaxf(m, fmaxf(fmaxf(v.x, v.y), fmaxf(v.z, v.w)));
    }
    #pragma unroll
    for (int off = 32; off; off >>= 1)
        m = fmaxf(m, __shfl_down(m, off, 64));
    __shared__ float sm[4];
    const int lane = threadIdx.x & 63, wv = threadIdx.x >> 6;
    if (lane == 0) sm[wv] = m;
    __syncthreads();
    if (threadIdx.x == 0) {
        m = fmaxf(fmaxf(sm[0], sm[1]), fmaxf(sm[2], sm[3]));
        atomicMax((int*)ws + b, __float_as_int(m));   // inputs >= 0
    }
}

__device__ __forceinline__ void loadrow(const float* __restrict__ xr,
                                        const float* __restrict__ yr,
                                        f2 xn[4], f2 yn[4]) {
    const f2* xp = (const f2*)xr;   // (r*368 + 2t)*4 is always 8B-aligned
    const f2* yp = (const f2*)yr;
    xn[0] = xp[0]; xn[1] = xp[1]; xn[2] = xp[2]; xn[3] = xp[3];
    yn[0] = yp[0]; yn[1] = yp[1]; yn[2] = yp[2]; yn[3] = yp[3];
}

#define FMA2(a, b, c) __builtin_elementwise_fma((a), (b), (c))

// Horizontal 7-sums for TWO adjacent windows, PACKED-FP32 version.
// xn[k] = (x[2k], x[2k+1]) sits in a 64-bit aligned VGPR pair -> VOP3P operand.
// Base window (elems 0..6) summed pairwise over k (v_pk_add/v_pk_fma), odd
// window (elems 1..7) derived incrementally in scalar. Output h[q] = f2{even,odd}.
// q: 0=x, 1=y, 2=s(xx+yy), 3=xy  (SSIM only ever consumes txx+tyy).
__device__ __forceinline__ void hsum2v(const f2 xn[4], const f2 yn[4], f2 h[4]) {
    const f2 px = xn[0] + xn[1] + xn[2];                    // 2 pk_add
    const f2 py = yn[0] + yn[1] + yn[2];                    // 2 pk_add
    f2 ps = xn[0] * xn[0];                                  // 1 pk_mul
    ps = FMA2(xn[1], xn[1], ps);
    ps = FMA2(xn[2], xn[2], ps);
    ps = FMA2(yn[0], yn[0], ps);
    ps = FMA2(yn[1], yn[1], ps);
    ps = FMA2(yn[2], yn[2], ps);                            // 5 pk_fma
    f2 pp = xn[0] * yn[0];
    pp = FMA2(xn[1], yn[1], pp);
    pp = FMA2(xn[2], yn[2], pp);                            // 1 mul + 2 fma

    const float x6 = xn[3].x, x7 = xn[3].y;
    const float y6 = yn[3].x, y7 = yn[3].y;
    const float x0 = xn[0].x, y0 = yn[0].x;

    const float hx = px.x + px.y + x6;                      // 2
    const float hy = py.x + py.y + y6;                      // 2
    const float hs = fmaf(x6, x6, fmaf(y6, y6, ps.x + ps.y));   // 3
    const float hxy = fmaf(x6, y6, pp.x + pp.y);            // 2

    h[0] = (f2){hx,  hx - x0 + x7};                                  // 2
    h[1] = (f2){hy,  hy - y0 + y7};                                  // 2
    h[2] = (f2){hs,  fmaf(x7, x7, fmaf(y7, y7,
                     fmaf(-x0, x0, fmaf(-y0, y0, hs))))};            // 4
    h[3] = (f2){hxy, fmaf(x7, y7, fmaf(-x0, y0, hxy))};              // 2
}

// Base: R3 structure exactly (register prefetch, no barriers/asm in the loop).
// NOTE: no min-waves clamp! __launch_bounds__(192,4) forced VGPR=64 previously and
// the ring spilled (WRITE_SIZE 96 KB -> 120 MB). Unconstrained alloc ~76-85 VGPR
// -> 6 waves/SIMD, 8 blocks/CU, 2048 blocks exactly fill the machine.
__global__ __launch_bounds__(192) void k_ssim(const float* __restrict__ X,
                                              const float* __restrict__ Y,
                                              float* __restrict__ ws) {
    const int t    = threadIdx.x;              // 0..191
    const int w    = t >> 6;
    const int lane = t & 63;
    const int b    = blockIdx.y;
    const int r0   = blockIdx.x * CHUNK;
    const int outRows = min(CHUNK, OH - r0);   // 10, or 4 for last chunk
    const int c    = 2 * t;                    // base output col
    const bool colOK = (c < OW);               // t <= 180

    const float dr  = ws[b];
    float C1 = 0.01f * dr; C1 *= C1;
    float C2 = 0.03f * dr; C2 *= C2;
    const f2 c1s   = (f2){C1 * 2401.0f, C1 * 2401.0f};   // scaled-domain constants
    const f2 c2s   = (f2){C2 * 2401.0f, C2 * 2401.0f};
    const f2 covn2 = (f2){2.0f * (49.0f / 48.0f), 2.0f * (49.0f / 48.0f)};
    const f2 covn  = (f2){49.0f / 48.0f, 49.0f / 48.0f};
    const f2 k49   = (f2){49.0f, 49.0f};
    const f2 two   = (f2){2.0f, 2.0f};

    const float* xb = X + (size_t)b * (H_ * W_) + c;
    const float* yb = Y + (size_t)b * (H_ * W_) + c;

    f2 accv = (f2){0.0f, 0.0f};

    if (colOK) {
        f2 ring[4][7];                         // [quantity][row slot], f2 over 2 cols
        f2 tot[4] = {};
        f2 h[4];
        f2 xn[4], yn[4];

        #pragma unroll
        for (int p = 0; p < 6; ++p) {          // prime 6 halo rows
            loadrow(xb + (size_t)(r0 + p) * W_, yb + (size_t)(r0 + p) * W_, xn, yn);
            hsum2v(xn, yn, h);
            #pragma unroll
            for (int q = 0; q < 4; ++q) {
                ring[q][p] = h[q];
                tot[q] += h[q];                // v_pk_add
            }
        }
        loadrow(xb + (size_t)(r0 + 6) * W_, yb + (size_t)(r0 + 6) * W_, xn, yn);

        for (int ii = 0; ii < outRows; ii += 7) {
            #pragma unroll
            for (int p = 0; p < 7; ++p) {      // ring slot == p (compile-time)
                const int i = ii + p;
                if (i >= outRows) break;       // block-uniform
                hsum2v(xn, yn, h);             // consume prefetched row r0+i+6
                if (i + 1 < outRows)           // prefetch row r0+i+7 (covered by VALU below)
                    loadrow(xb + (size_t)(r0 + i + 7) * W_, yb + (size_t)(r0 + i + 7) * W_, xn, yn);

                #pragma unroll
                for (int q = 0; q < 4; ++q)
                    tot[q] += h[q];            // 4x v_pk_add

                {   // SSIM for both columns, fully packed (2 scalar rcp only)
                    const f2 tx = tot[0], ty = tot[1], ts = tot[2], txy = tot[3];
                    const f2 pxy = tx * ty;
                    const f2 A1  = FMA2(pxy, two, c1s);
                    const f2 s2  = FMA2(tx, tx, ty * ty);
                    const f2 B1  = s2 + c1s;
                    const f2 mxy = FMA2(k49, txy, -pxy);
                    const f2 A2  = FMA2(covn2, mxy, c2s);
                    const f2 vs  = FMA2(k49, ts, -s2);
                    const f2 B2  = FMA2(covn, vs, c2s);
                    const f2 den = B1 * B2;
                    f2 rv;
                    rv.x = __builtin_amdgcn_rcpf(den.x);
                    rv.y = __builtin_amdgcn_rcpf(den.y);
                    accv = FMA2(A1 * A2, rv, accv);
                }

                const int sn = (p + 6) % 7;    // retire slot p, insert new in slot sn
                #pragma unroll
                for (int q = 0; q < 4; ++q) {
                    tot[q] -= ring[q][p];      // v_pk_sub
                    ring[q][sn] = h[q];
                }
            }
        }
    }

    // wave reduce, LDS across 3 waves, ONE scattered atomic per block. No fences!
    float acc = accv.x + accv.y;
    #pragma unroll
    for (int off = 32; off; off >>= 1)
        acc += __shfl_down(acc, off, 64);
    __shared__ float sm[3];
    if (lane == 0) sm[w] = acc;
    __syncthreads();
    if (t == 0) {
        const float s = sm[0] + sm[1] + sm[2];
        const int blk = blockIdx.y * NCHUNK + blockIdx.x;
        atomicAdd(ws + SLOT0 + (blk & (GROUPS - 1)) * STRIDE, s);  // 64 independent lines
    }
}

__global__ __launch_bounds__(64) void k_fin(const float* __restrict__ ws,
                                            float* __restrict__ out) {
    float v = ws[SLOT0 + threadIdx.x * STRIDE];   // kernel boundary orders prior atomics
    #pragma unroll
    for (int off = 32; off; off >>= 1)
        v += __shfl_down(v, off, 64);
    if (threadIdx.x == 0)
        out[0] = 1.0f - v * (1.0f / (32.0f * 634.0f * 362.0f));
}

extern "C" void kernel_launch(void* const* d_in, const int* in_sizes, int n_in,
                              void* d_out, int out_size, void* d_ws, size_t ws_size,
                              hipStream_t stream) {
    const float* X = (const float*)d_in[0];   // 'output'
    const float* Y = (const float*)d_in[1];   // 'target'
    float* ws = (float*)d_ws;

    k_max<<<dim3(1024), dim3(256), 0, stream>>>(Y, ws);
    k_ssim<<<dim3(NCHUNK, B_), dim3(192), 0, stream>>>(X, Y, ws);
    k_fin<<<dim3(1), dim3(64), 0, stream>>>(ws, (float*)d_out);
}